// Round 15
// baseline (436.874 us; speedup 1.0000x reference)
//
#include <hip/hip_runtime.h>
#include <hip/hip_bf16.h>

// Dust3R transformer block. fp32 I/O; bf16 MFMA GEMMs + bf16 MFMA flash attention.
// B=2 N=3072 C=768 H=12 HD=64.
// ws layout (liveness reuse, peak 99090432 B):
//   xnb  bf16 [6144,768]   @ 0          (live 1-2, 6-7)
//   Qb   bf16 [24,3072,64] @ 9437184    (live 3-4)
//   Kb   bf16 [24,3072,64] @ 18874368   (live 3-4)
//   x1   f32  [6144,768]   @ 9437184    (live 5-8, overlays dead Qb+Kb)
//   Vt   bf16 [24,64,3072] @ 28311552   (live 3-4)
//   obb  bf16 [6144,768]   @ 37748736   (live 4-5)
//   hb   bf16 [6144,3072]  @ 47185920   (live 7-8)
//   wqkvb @ 84934656, wprojb @ 88473600, wfc1b @ 89653248, wfc2b @ 94371840
//
// fattn ledger (ALL measured):
//   R9 v3b: 127.5 | R10 spills: 217 | R11 9w/CU: 141 | R12: 131 | R13: 231 |
//   R14 VALU-rowsums + FENCE REMOVED -> spills: 165 (confounded: spills were
//   from fence removal, not the rowsum change) | R20 prefetch rotation: null |
//   R22 cvt piggyback: fattn absorbs 21MB cvt traffic at +2us.
//   R24 (THIS): v3c-FENCE-KEPT — the un-confounded half of R14: l[qs] MFMAs
//   (8/72 = 11% of MFMA issue, 16 AGPR + ones8) -> VALU adds on in-register
//   exp2 results + shfl_xor(16,32) reduce. Fence stays (schedule anchor).
//   TRIPWIRE: WRITE_SIZE ~23 MB; jump to >40 MB = R14-style spills -> revert.
//
// mgemm/pipeline ledger: R15 XCD swizzle 455.6->448.9 | R16 BK 32->64 ->440.1 |
// R17 dbuf@BK32 ~null | R18 RoPE-fused qkvgemm + cvt/ln fuse ->422.8 |
// R19 BK=64+dbuf ->417.9 | R21 proj/fc2 NT=128 regression | R22 cvt piggyback
// ->413.4 | R23 fc1 NT=64 (2304 blocks = exactly 3 rounds @768 cap) ->401.1.
// CAPACITY MODEL (validated 3x): NT=128: 64KB LDS + ~154 regs -> 2 blocks/CU
// (cap 512). NT=64: 48KB LDS + ~122 regs -> 3 blocks/CU (cap 768).
// 8-phase template REJECTED for this problem: 256^2 tiles -> 288 blocks @ 1
// block/CU = 1.125 rounds = 56% round-eff (quantization-killed); 128^2+8ph
// is a measured null (m232).

#define Nn 3072
#define Cc 768
#define Hh 12
#define Mm 6144   // B*N
#define QKVCVT 1728    // wqkv: 2304*768/1024 blocks

typedef unsigned short ushort_t;
typedef unsigned int u32;
using s8v = __attribute__((ext_vector_type(8))) short;   // 8 bf16 (4 VGPRs)
using f4v = __attribute__((ext_vector_type(4))) float;   // MFMA acc

__device__ __forceinline__ ushort_t f2b(float x){
  u32 u = __float_as_uint(x);
  return (ushort_t)((u + 0x7fffu + ((u >> 16) & 1u)) >> 16);  // RNE
}
__device__ __forceinline__ u32 pack2(float a, float b){
  return (u32)f2b(a) | ((u32)f2b(b) << 16);
}
__device__ __forceinline__ u32 pack2t(float a, float b){   // truncation pack (cheap)
  return (__float_as_uint(a) >> 16) | (__float_as_uint(b) & 0xffff0000u);
}
__device__ __forceinline__ float b2f(ushort_t u){
  return __uint_as_float(((u32)u) << 16);
}

#define GLD16(g, l) __builtin_amdgcn_global_load_lds( \
    (const __attribute__((address_space(1))) u32*)(g), \
    (__attribute__((address_space(3))) u32*)(l), 16, 0, 0)

// ---------------- fused: wqkv fp32->bf16 (blocks 0..1727) + LN1 (rest) ----------
__global__ __launch_bounds__(256) void cvtln_kernel(
    const float* __restrict__ wq, ushort_t* __restrict__ wqb,
    const float* __restrict__ xin, const float* __restrict__ g1,
    const float* __restrict__ be1, ushort_t* __restrict__ xout)
{
  int tid = threadIdx.x;
  if (blockIdx.x < QKVCVT) {
    int i = (blockIdx.x*256 + tid)*4;
    float4 v = *(const float4*)(wq + i);
    uint2 p; p.x = pack2(v.x, v.y); p.y = pack2(v.z, v.w);
    *(uint2*)(wqb + i) = p;
    return;
  }
  int row = blockIdx.x - QKVCVT;
  size_t base = (size_t)row * Cc;
  float v[3];
  #pragma unroll
  for (int i = 0; i < 3; ++i) v[i] = xin[base + tid + i*256];
  __shared__ float red[8];
  float s = v[0]+v[1]+v[2];
  #pragma unroll
  for (int off=32; off; off>>=1) s += __shfl_xor(s, off);
  int wid = tid >> 6, lane = tid & 63;
  if (lane==0) red[wid] = s;
  __syncthreads();
  float mean = (red[0]+red[1]+red[2]+red[3]) * (1.f/Cc);
  float dd = 0.f;
  #pragma unroll
  for (int i=0;i<3;++i){ float t = v[i]-mean; dd += t*t; }
  #pragma unroll
  for (int off=32; off; off>>=1) dd += __shfl_xor(dd, off);
  if (lane==0) red[4+wid] = dd;
  __syncthreads();
  float var  = (red[4]+red[5]+red[6]+red[7]) * (1.f/Cc);
  float rstd = rsqrtf(var + 1e-5f);
  #pragma unroll
  for (int i=0;i<3;++i){
    int idx = tid + i*256;
    xout[base+idx] = f2b((v[i]-mean)*rstd*g1[idx] + be1[idx]);
  }
}

// ---------------- LayerNorm (f32 in, bf16 out) — used for LN2 ----------------
__global__ __launch_bounds__(256) void ln_kernel(const float* __restrict__ in,
    const float* __restrict__ g, const float* __restrict__ be, ushort_t* __restrict__ out)
{
  int row = blockIdx.x;
  int tid = threadIdx.x;
  size_t base = (size_t)row * Cc;
  float v[3];
  #pragma unroll
  for (int i = 0; i < 3; ++i) v[i] = in[base + tid + i*256];
  __shared__ float red[8];
  float s = v[0]+v[1]+v[2];
  #pragma unroll
  for (int off=32; off; off>>=1) s += __shfl_xor(s, off);
  int wid = tid >> 6, lane = tid & 63;
  if (lane==0) red[wid] = s;
  __syncthreads();
  float mean = (red[0]+red[1]+red[2]+red[3]) * (1.f/Cc);
  float d = 0.f;
  #pragma unroll
  for (int i=0;i<3;++i){ float t = v[i]-mean; d += t*t; }
  #pragma unroll
  for (int off=32; off; off>>=1) d += __shfl_xor(d, off);
  if (lane==0) red[4+wid] = d;
  __syncthreads();
  float var  = (red[4]+red[5]+red[6]+red[7]) * (1.f/Cc);
  float rstd = rsqrtf(var + 1e-5f);
  #pragma unroll
  for (int i=0;i<3;++i){
    int idx = tid + i*256;
    out[base+idx] = f2b((v[i]-mean)*rstd*g[idx] + be[idx]);
  }
}

// ---------------- MFMA GEMM: out[M,Nd] = A[M,K] @ W[Nd,K]^T (+epilogue) ----------------
// Tile 128 x NT (NT=128 or 64), BK=64 (two stacked [*][32] halves), double-buffered.
// EPI: 1 +bias+resid_f32 -> f32 | 2 +bias,GELU->bf16
// XCD-aware block swizzle (R15): all grids % 8 == 0, remap bijective.
template<int EPI, int NT>
__global__ __launch_bounds__(256) void mgemm_kernel(
    const ushort_t* __restrict__ A, const ushort_t* __restrict__ W,
    const float* __restrict__ bias, const float* __restrict__ residf,
    void* __restrict__ outv, int Nd, int K)
{
  constexpr int JT = NT/32;           // n-subtiles per wave
  __shared__ __align__(16) ushort_t As[2][2][128*32];   // [buf][kk][row*32]
  __shared__ __align__(16) ushort_t Ws[2][2][NT*32];
  int tid = threadIdx.x;
  int w = tid >> 6, lane = tid & 63;
  int g = lane >> 4, c = lane & 15;
  int wr = w >> 1, wc = w & 1;
  int gx = gridDim.x;
  int nwg = gx * gridDim.y;
  int lin = blockIdx.y * gx + blockIdx.x;
  int swz = (lin & 7) * (nwg >> 3) + (lin >> 3);
  int bx = swz % gx, by = swz / gx;
  int m0 = by * 128, n0 = bx * NT;
  int schunk = (lane & 3) * 8;
  const ushort_t* Ag = A + (size_t)(m0 + w*32 + (lane >> 2))*K + schunk;
  const ushort_t* Wg;
  if constexpr (NT == 128) Wg = W + (size_t)(n0 + w*32 + (lane >> 2))*K + schunk;
  else                     Wg = W + (size_t)(n0 + w*16 + (lane >> 2))*K + schunk;
  int wAoff = w*1024;
  int wWoff = (NT == 128) ? w*1024 : w*512;
  f4v acc[4][JT] = {};

  auto stage = [&](int bf, int k0s){
    GLD16(Ag + k0s,             &As[bf][0][wAoff]);
    GLD16(Ag + 16*K + k0s,      &As[bf][0][wAoff + 512]);
    GLD16(Ag + k0s + 32,        &As[bf][1][wAoff]);
    GLD16(Ag + 16*K + k0s + 32, &As[bf][1][wAoff + 512]);
    GLD16(Wg + k0s,             &Ws[bf][0][wWoff]);
    GLD16(Wg + k0s + 32,        &Ws[bf][1][wWoff]);
    if constexpr (NT == 128) {
      GLD16(Wg + 16*K + k0s,      &Ws[bf][0][wWoff + 512]);
      GLD16(Wg + 16*K + k0s + 32, &Ws[bf][1][wWoff + 512]);
    }
  };

  stage(0, 0);
  __syncthreads();

  int nk = K >> 6;
  for (int t = 0; t < nk; ++t) {
    int cur = t & 1;
    if (t + 1 < nk) stage(cur ^ 1, (t + 1) << 6);
    #pragma unroll
    for (int kk = 0; kk < 2; ++kk){
      s8v af[4], wf[JT];
      #pragma unroll
      for (int i=0;i<4;++i) af[i] = *(const s8v*)&As[cur][kk][(wr*64 + i*16 + c)*32 + g*8];
      #pragma unroll
      for (int j=0;j<JT;++j) wf[j] = *(const s8v*)&Ws[cur][kk][(wc*(NT/2) + j*16 + c)*32 + g*8];
      #pragma unroll
      for (int i=0;i<4;++i)
        #pragma unroll
        for (int j=0;j<JT;++j)
          acc[i][j] = __builtin_amdgcn_mfma_f32_16x16x32_bf16(af[i], wf[j], acc[i][j], 0,0,0);
    }
    __syncthreads();
  }
  #pragma unroll
  for (int j=0;j<JT;++j){
    int col = n0 + wc*(NT/2) + j*16 + c;
    float bv = bias[col];
    #pragma unroll
    for (int i=0;i<4;++i){
      int row0 = m0 + wr*64 + i*16 + g*4;
      #pragma unroll
      for (int r=0;r<4;++r){
        float v = acc[i][j][r];
        size_t off = (size_t)(row0 + r)*Nd + col;
        if (EPI == 2) {
          float t = v + bv;
          ((ushort_t*)outv)[off] = f2b(0.5f*t*(1.0f + erff(t*0.70710678118654752f)));
        } else {
          ((float*)outv)[off] = v + bv + residf[off];
        }
      }
    }
  }
}

// ---------------- QKV GEMM with fused RoPE repack epilogue (R18) ----------------
// BK=64 dbuf main loop (R19). Epilogue: region = n0/768 (0=q,1=k,2=v; blocks
// never straddle since 768%128==0). q/k: RoPE pairs (acc[i][0],acc[i][1]) with
// y-tables, (acc[i][2],acc[i][3]) with x-tables, table idx c / 16+c, q scaled
// by 0.125*log2e. v: uint2 of 4 consecutive tokens at fixed dim into Vt.
__global__ __launch_bounds__(256) void qkvgemm_kernel(
    const ushort_t* __restrict__ A, const ushort_t* __restrict__ W,
    const float* __restrict__ cx, const float* __restrict__ sx,
    const float* __restrict__ cy, const float* __restrict__ sy,
    ushort_t* __restrict__ Qb, ushort_t* __restrict__ Kb, ushort_t* __restrict__ Vt)
{
  constexpr int NT = 128, JT = 4, K = 768;
  __shared__ __align__(16) ushort_t As[2][2][128*32];
  __shared__ __align__(16) ushort_t Ws[2][2][NT*32];
  int tid = threadIdx.x;
  int w = tid >> 6, lane = tid & 63;
  int g = lane >> 4, c = lane & 15;
  int wr = w >> 1, wc = w & 1;
  int gx = gridDim.x;
  int nwg = gx * gridDim.y;
  int lin = blockIdx.y * gx + blockIdx.x;
  int swz = (lin & 7) * (nwg >> 3) + (lin >> 3);
  int bx = swz % gx, by = swz / gx;
  int m0 = by * 128, n0 = bx * NT;
  int schunk = (lane & 3) * 8;
  const ushort_t* Ag = A + (size_t)(m0 + w*32 + (lane >> 2))*K + schunk;
  const ushort_t* Wg = W + (size_t)(n0 + w*32 + (lane >> 2))*K + schunk;
  int wAoff = w*1024;
  f4v acc[4][JT] = {};

  auto stage = [&](int bf, int k0s){
    GLD16(Ag + k0s,             &As[bf][0][wAoff]);
    GLD16(Ag + 16*K + k0s,      &As[bf][0][wAoff + 512]);
    GLD16(Ag + k0s + 32,        &As[bf][1][wAoff]);
    GLD16(Ag + 16*K + k0s + 32, &As[bf][1][wAoff + 512]);
    GLD16(Wg + k0s,             &Ws[bf][0][wAoff]);
    GLD16(Wg + 16*K + k0s,      &Ws[bf][0][wAoff + 512]);
    GLD16(Wg + k0s + 32,        &Ws[bf][1][wAoff]);
    GLD16(Wg + 16*K + k0s + 32, &Ws[bf][1][wAoff + 512]);
  };

  stage(0, 0);
  __syncthreads();

  int nk = K >> 6;
  for (int t = 0; t < nk; ++t) {
    int cur = t & 1;
    if (t + 1 < nk) stage(cur ^ 1, (t + 1) << 6);
    #pragma unroll
    for (int kk = 0; kk < 2; ++kk){
      s8v af[4], wf[JT];
      #pragma unroll
      for (int i=0;i<4;++i) af[i] = *(const s8v*)&As[cur][kk][(wr*64 + i*16 + c)*32 + g*8];
      #pragma unroll
      for (int j=0;j<JT;++j) wf[j] = *(const s8v*)&Ws[cur][kk][(wc*64 + j*16 + c)*32 + g*8];
      #pragma unroll
      for (int i=0;i<4;++i)
        #pragma unroll
        for (int j=0;j<JT;++j)
          acc[i][j] = __builtin_amdgcn_mfma_f32_16x16x32_bf16(af[i], wf[j], acc[i][j], 0,0,0);
    }
    __syncthreads();
  }

  int region = n0 / 768;                 // 0=q, 1=k, 2=v (uniform per block)
  int h = ((n0 - region*768) >> 6) + wc; // head index
  if (region < 2) {
    float sc = region ? 1.0f : 0.18033688011112042f;   // q: 0.125 * log2(e)
    ushort_t* dstb = region ? Kb : Qb;
    #pragma unroll
    for (int i=0;i<4;++i){
      int row0 = m0 + wr*64 + i*16 + g*4;
      #pragma unroll
      for (int r=0;r<4;++r){
        int row = row0 + r;
        int b = row >= Nn;
        int nt = row - (b ? Nn : 0);
        size_t tb = (size_t)nt*32 + c;
        float vlo0 = acc[i][0][r], vhi0 = acc[i][1][r];
        float vlo1 = acc[i][2][r], vhi1 = acc[i][3][r];
        float o0 = (vlo0*cy[tb]    - vhi0*sy[tb])    * sc;
        float o1 = (vhi0*cy[tb+16] + vlo0*sy[tb+16]) * sc;
        float o2 = (vlo1*cx[tb]    - vhi1*sx[tb])    * sc;
        float o3 = (vhi1*cx[tb+16] + vlo1*sx[tb+16]) * sc;
        ushort_t* dp = dstb + ((size_t)(b*Hh + h)*Nn + nt)*64;
        dp[c]      = f2b(o0);
        dp[16 + c] = f2b(o1);
        dp[32 + c] = f2b(o2);
        dp[48 + c] = f2b(o3);
      }
    }
  } else {
    #pragma unroll
    for (int i=0;i<4;++i){
      int row0 = m0 + wr*64 + i*16 + g*4;
      int b = row0 >= Nn;
      int nt0 = row0 - (b ? Nn : 0);
      #pragma unroll
      for (int j=0;j<4;++j){
        int d = j*16 + c;
        uint2 pk;
        pk.x = pack2(acc[i][j][0], acc[i][j][1]);
        pk.y = pack2(acc[i][j][2], acc[i][j][3]);
        *(uint2*)&Vt[((size_t)(b*Hh + h)*64 + d)*Nn + nt0] = pk;
      }
    }
  }
}

// ---------------- MFMA flash attention v3c (fence kept) + cvt piggyback ----------
// split-key waves, XCD-pinned heads: fattn blocks at y<48: (x=bh=24, y=qtile=48)
// -> xcd = bh%8, KV working set 2.3 MB < 4 MB L2/XCD. K/V direct global->VGPR.
// Blocks y>=48 (5184 tiny blocks) convert wproj/wfc1/wfc2 fp32->bf16 (R22).
// R24: row-sums moved from l[qs] MFMAs to VALU adds on the in-register exp2
// results + shfl_xor(16,32) — the UN-confounded half of R14 (fence KEPT; R14's
// spills were from fence removal). -8 MFMA/iter (-11%), -20 regs.
// DO NOT: unroll/rotate (R9/R20), remove the fence (R14), smaller key tiles
// (R13), wave re-balance (R10-R12) — all measured slower.
__global__ __launch_bounds__(256, 3) void fattn_kernel(
    const ushort_t* __restrict__ Qb, const ushort_t* __restrict__ Kb,
    const ushort_t* __restrict__ Vt, ushort_t* __restrict__ ob,
    const float* __restrict__ wp,  ushort_t* __restrict__ wpb,
    const float* __restrict__ w1,  ushort_t* __restrict__ w1b,
    const float* __restrict__ w2,  ushort_t* __restrict__ w2b)
{
  int tid = threadIdx.x;
  if (blockIdx.y >= 48) {
    // weight-convert path: wproj 589824 | wfc1 2359296 | wfc2 2359296 elems
    int cvtIdx = (blockIdx.y - 48)*24 + blockIdx.x;
    int i = cvtIdx*1024 + tid*4;
    const float* src; ushort_t* dst;
    if (i < 589824)       { src = wp + i;            dst = wpb + i; }
    else if (i < 2949120) { src = w1 + (i-589824);   dst = w1b + (i-589824); }
    else                  { src = w2 + (i-2949120);  dst = w2b + (i-2949120); }
    float4 v = *(const float4*)src;
    uint2 p; p.x = pack2(v.x, v.y); p.y = pack2(v.z, v.w);
    *(uint2*)dst = p;
    return;
  }
  __shared__ __align__(16) char smem[36864];  // [w][qs][16][72] bf16 P; aliases [w][64][72] Or
  __shared__ float Lred[256];
  int bh = blockIdx.x;
  int q0 = blockIdx.y * 64;
  int w = tid >> 6, lane = tid & 63, g = lane >> 4, c = lane & 15;

  const ushort_t* kbase = Kb + (size_t)bh*Nn*64;
  const ushort_t* vbase = Vt + (size_t)bh*64*Nn;

  s8v qf0[4], qf1[4];
  #pragma unroll
  for (int qs=0;qs<4;++qs){
    const ushort_t* qp = Qb + ((size_t)bh*Nn + q0 + qs*16 + c)*64;
    qf0[qs] = *(const s8v*)(qp + g*8);
    qf1[qs] = *(const s8v*)(qp + 32 + g*8);
  }

  f4v o[4][4] = {};
  float rs[4] = {0.f, 0.f, 0.f, 0.f};
  ushort_t* pw = (ushort_t*)smem + w*4608;   // wave-private 4*16*72

  for (int it = 0; it < 12; ++it){
    int key0 = (it*4 + w) * 64;
    // K fragments direct from global (A-operand: A[m=key][k=dim])
    s8v ka[4], kb2[4];
    #pragma unroll
    for (int ks=0;ks<4;++ks){
      const ushort_t* kr = kbase + (size_t)(key0 + ks*16 + c)*64 + g*8;
      ka[ks]  = *(const s8v*)(kr);
      kb2[ks] = *(const s8v*)(kr + 32);
    }
    // S^T = K·Q^T per q-subtile; p = exp2(s) -> wave-private LDS; rowsums in VALU
    #pragma unroll
    for (int qs=0;qs<4;++qs){
      #pragma unroll
      for (int ks=0;ks<4;++ks){
        f4v z = {0,0,0,0};
        z = __builtin_amdgcn_mfma_f32_16x16x32_bf16(ka[ks],  qf0[qs], z, 0,0,0);
        z = __builtin_amdgcn_mfma_f32_16x16x32_bf16(kb2[ks], qf1[qs], z, 0,0,0);
        float e0 = __builtin_amdgcn_exp2f(z[0]);
        float e1 = __builtin_amdgcn_exp2f(z[1]);
        float e2 = __builtin_amdgcn_exp2f(z[2]);
        float e3 = __builtin_amdgcn_exp2f(z[3]);
        rs[qs] += (e0+e1)+(e2+e3);
        uint2 pk;
        pk.x = pack2t(e0, e1);
        pk.y = pack2t(e2, e3);
        *(uint2*)&pw[qs*1152 + c*72 + ks*16 + g*4] = pk;
      }
    }
    asm volatile("s_waitcnt lgkmcnt(0)" ::: "memory");
    // V^T fragments direct from global (A-operand: A[m=dim][k=key])
    s8v va[4], vb[4];
    #pragma unroll
    for (int d=0;d<4;++d){
      const ushort_t* vr = vbase + (size_t)(d*16 + c)*Nn + key0 + g*8;
      va[d] = *(const s8v*)(vr);
      vb[d] = *(const s8v*)(vr + 32);
    }
    #pragma unroll
    for (int qs=0;qs<4;++qs){
      s8v pf0 = *(const s8v*)&pw[qs*1152 + c*72 + g*8];
      s8v pf1 = *(const s8v*)&pw[qs*1152 + c*72 + 32 + g*8];
      #pragma unroll
      for (int d=0;d<4;++d){
        o[qs][d] = __builtin_amdgcn_mfma_f32_16x16x32_bf16(va[d], pf0, o[qs][d], 0,0,0);
        o[qs][d] = __builtin_amdgcn_mfma_f32_16x16x32_bf16(vb[d], pf1, o[qs][d], 0,0,0);
      }
    }
  }

  // finalize row-sums: combine the 4 g-groups (lanes c, c+16, c+32, c+48)
  #pragma unroll
  for (int qs=0;qs<4;++qs){
    rs[qs] += __shfl_xor(rs[qs], 16);
    rs[qs] += __shfl_xor(rs[qs], 32);
  }

  // partials -> LDS (own slice; in-order DS makes this safe after the last P read)
  ushort_t* Or = (ushort_t*)smem;   // [w*64 + qrow][72]
  #pragma unroll
  for (int qs=0;qs<4;++qs){
    #pragma unroll
    for (int d=0;d<4;++d){
      uint2 pk;
      pk.x = pack2(o[qs][d][0], o[qs][d][1]);
      pk.y = pack2(o[qs][d][2], o[qs][d][3]);
      *(uint2*)&Or[(w*64 + qs*16 + c)*72 + d*16 + g*4] = pk;
    }
    Lred[w*64 + qs*16 + c] = rs[qs];   // all 4 g-groups hold the same value
  }
  __syncthreads();

  // combine: thread t owns (qrow = t>>2, dims (t&3)*16..+16)
  int qrow = tid >> 2, dseg = (tid & 3) * 16;
  float acc[16] = {};
  #pragma unroll
  for (int w2=0;w2<4;++w2){
    const ushort_t* base = &Or[(w2*64 + qrow)*72 + dseg];
    uint4 u0 = *(const uint4*)(base);
    uint4 u1 = *(const uint4*)(base + 8);
    u32 uu[8] = {u0.x,u0.y,u0.z,u0.w,u1.x,u1.y,u1.z,u1.w};
    #pragma unroll
    for (int j=0;j<8;++j){
      acc[j*2]   += b2f((ushort_t)(uu[j] & 0xffff));
      acc[j*2+1] += b2f((ushort_t)(uu[j] >> 16));
    }
  }
  float rl = 1.0f / (Lred[qrow] + Lred[64+qrow] + Lred[128+qrow] + Lred[192+qrow]);
  int b = bh / Hh, h = bh - b*Hh;
  ushort_t* op = ob + ((size_t)b*Nn + q0 + qrow)*768 + h*64 + dseg;
  uint4 w0_, w1_;
  w0_.x = pack2(acc[0]*rl, acc[1]*rl);   w0_.y = pack2(acc[2]*rl, acc[3]*rl);
  w0_.z = pack2(acc[4]*rl, acc[5]*rl);   w0_.w = pack2(acc[6]*rl, acc[7]*rl);
  w1_.x = pack2(acc[8]*rl, acc[9]*rl);   w1_.y = pack2(acc[10]*rl, acc[11]*rl);
  w1_.z = pack2(acc[12]*rl, acc[13]*rl); w1_.w = pack2(acc[14]*rl, acc[15]*rl);
  *(uint4*)(op)     = w0_;
  *(uint4*)(op + 8) = w1_;
}

extern "C" void kernel_launch(void* const* d_in, const int* in_sizes, int n_in,
                              void* d_out, int out_size, void* d_ws, size_t ws_size,
                              hipStream_t stream)
{
  const float* x      = (const float*)d_in[0];
  const float* w_qkv  = (const float*)d_in[1];
  const float* w_proj = (const float*)d_in[2];
  const float* b_proj = (const float*)d_in[3];
  const float* g1     = (const float*)d_in[4];
  const float* be1    = (const float*)d_in[5];
  const float* g2     = (const float*)d_in[6];
  const float* be2    = (const float*)d_in[7];
  const float* w_fc1  = (const float*)d_in[8];
  const float* b_fc1  = (const float*)d_in[9];
  const float* w_fc2  = (const float*)d_in[10];
  const float* b_fc2  = (const float*)d_in[11];
  const float* cx     = (const float*)d_in[12];
  const float* sx     = (const float*)d_in[13];
  const float* cy     = (const float*)d_in[14];
  const float* sy     = (const float*)d_in[15];
  float* out = (float*)d_out;

  char* ws = (char*)d_ws;
  ushort_t* xnb   = (ushort_t*)(ws);
  ushort_t* Qb    = (ushort_t*)(ws + 9437184);
  ushort_t* Kb    = (ushort_t*)(ws + 18874368);
  float*    x1    = (float*)   (ws + 9437184);    // overlays dead Qb+Kb (live 5-8)
  ushort_t* Vt    = (ushort_t*)(ws + 28311552);
  ushort_t* obb   = (ushort_t*)(ws + 37748736);
  ushort_t* hb    = (ushort_t*)(ws + 47185920);
  ushort_t* wqkvb = (ushort_t*)(ws + 84934656);
  ushort_t* wprojb= (ushort_t*)(ws + 88473600);
  ushort_t* wfc1b = (ushort_t*)(ws + 89653248);
  ushort_t* wfc2b = (ushort_t*)(ws + 94371840);

  // 0+1) wqkv -> bf16 AND LN1 -> bf16, one fused launch (other weights piggyback on fattn)
  cvtln_kernel<<<QKVCVT + Mm, 256, 0, stream>>>(w_qkv, wqkvb, x, g1, be1, xnb);

  // 2+3) QKV GEMM with fused RoPE repack -> Qb, Kb, Vt
  qkvgemm_kernel<<<dim3(2304/128, Mm/128), 256, 0, stream>>>(
      xnb, wqkvb, cx, sx, cy, sy, Qb, Kb, Vt);
  // 4) fattn v3c (y<48) + wproj/wfc1/wfc2 conversion piggyback (y>=48, 5184 blocks)
  fattn_kernel<<<dim3(24, 48 + 216), 256, 0, stream>>>(
      Qb, Kb, Vt, obb, w_proj, wprojb, w_fc1, wfc1b, w_fc2, wfc2b);
  // 5) x1 = x + obb @ w_proj^T + b_proj (f32) — 128x64 tiles, 576 blocks (tail-free @3/CU)
  mgemm_kernel<1,64><<<dim3(768/64, Mm/128), 256, 0, stream>>>(obb, wprojb, b_proj, x, x1, 768, 768);
  // 6) LN2 -> bf16
  ln_kernel<<<Mm, 256, 0, stream>>>(x1, g2, be2, xnb);
  // 7) h = gelu(xn @ w_fc1^T + b_fc1) -> bf16 — NT=64: 2304 blocks = exactly 3 rounds @768 cap
  mgemm_kernel<2,64><<<dim3(3072/64, Mm/128), 256, 0, stream>>>(xnb, wfc1b, b_fc1, nullptr, hb, 3072, 768);
  // 8) out = x1 + h @ w_fc2^T + b_fc2 (f32) — 128x64 tiles, 576 blocks (tail-free @3/CU)
  mgemm_kernel<1,64><<<dim3(768/64, Mm/128), 256, 0, stream>>>(hb, wfc2b, b_fc2, x1, out, 768, 3072);
}

// Round 16
// 400.980 us; speedup vs baseline: 1.0895x; 1.0895x over previous
//
#include <hip/hip_runtime.h>
#include <hip/hip_bf16.h>

// Dust3R transformer block. fp32 I/O; bf16 MFMA GEMMs + bf16 MFMA flash attention.
// B=2 N=3072 C=768 H=12 HD=64.
// ws layout (liveness reuse, peak 99090432 B):
//   xnb  bf16 [6144,768]   @ 0          (live 1-2, 6-7)
//   Qb   bf16 [24,3072,64] @ 9437184    (live 3-4)
//   Kb   bf16 [24,3072,64] @ 18874368   (live 3-4)
//   x1   f32  [6144,768]   @ 9437184    (live 5-8, overlays dead Qb+Kb)
//   Vt   bf16 [24,64,3072] @ 28311552   (live 3-4)
//   obb  bf16 [6144,768]   @ 37748736   (live 4-5)
//   hb   bf16 [6144,3072]  @ 47185920   (live 7-8)
//   wqkvb @ 84934656, wprojb @ 88473600, wfc1b @ 89653248, wfc2b @ 94371840
//
// fattn ledger (ALL measured; v3b IS THE OPTIMUM — 8 attempts, 8 losses):
//   R9 v3b: 127.5 | R10 spills: 217 | R11 9w/CU: 141 | R12: 131 | R13: 231 |
//   R14 VALU-rowsums+fence-gone: 165 | R20 prefetch rotation: null |
//   R24 VALU-rowsums FENCE KEPT: 166.5, WRITE 23->44.9 MB — the rowsum
//   substitution ITSELF spills (e0..e3 + rs[4] live ranges exceed the
//   (256,3) 170-reg cap; l-MFMA accumulates in AGPRs = register-cheapest).
//   R14 was not confounded. DO NOT TOUCH v3b. l-MFMAs are load-bearing.
//
// mgemm/pipeline ledger: R15 XCD swizzle 455.6->448.9 | R16 BK 32->64 ->440.1 |
// R17 dbuf@BK32 ~null | R18 RoPE-fused qkvgemm + cvt/ln fuse ->422.8 |
// R19 BK=64+dbuf ->417.9 | R21 proj/fc2 NT=128 regression | R22 cvt piggyback
// ->413.4 | R23 fc1 NT=64 ->401.1 (BEST, restored here byte-exact).
// CAPACITY MODEL (validated 3x): NT=128: 64KB LDS + ~154 regs -> 2 blocks/CU
// (cap 512). NT=64: 48KB LDS + ~122 regs -> 3 blocks/CU (cap 768).
// 8-phase template rejected at this size (288 blocks @ 1/CU = 56% round-eff).

#define Nn 3072
#define Cc 768
#define Hh 12
#define Mm 6144   // B*N
#define QKVCVT 1728    // wqkv: 2304*768/1024 blocks

typedef unsigned short ushort_t;
typedef unsigned int u32;
using s8v = __attribute__((ext_vector_type(8))) short;   // 8 bf16 (4 VGPRs)
using f4v = __attribute__((ext_vector_type(4))) float;   // MFMA acc

__device__ __forceinline__ ushort_t f2b(float x){
  u32 u = __float_as_uint(x);
  return (ushort_t)((u + 0x7fffu + ((u >> 16) & 1u)) >> 16);  // RNE
}
__device__ __forceinline__ u32 pack2(float a, float b){
  return (u32)f2b(a) | ((u32)f2b(b) << 16);
}
__device__ __forceinline__ u32 pack2t(float a, float b){   // truncation pack (cheap)
  return (__float_as_uint(a) >> 16) | (__float_as_uint(b) & 0xffff0000u);
}
__device__ __forceinline__ float b2f(ushort_t u){
  return __uint_as_float(((u32)u) << 16);
}

#define GLD16(g, l) __builtin_amdgcn_global_load_lds( \
    (const __attribute__((address_space(1))) u32*)(g), \
    (__attribute__((address_space(3))) u32*)(l), 16, 0, 0)

// ---------------- fused: wqkv fp32->bf16 (blocks 0..1727) + LN1 (rest) ----------
__global__ __launch_bounds__(256) void cvtln_kernel(
    const float* __restrict__ wq, ushort_t* __restrict__ wqb,
    const float* __restrict__ xin, const float* __restrict__ g1,
    const float* __restrict__ be1, ushort_t* __restrict__ xout)
{
  int tid = threadIdx.x;
  if (blockIdx.x < QKVCVT) {
    int i = (blockIdx.x*256 + tid)*4;
    float4 v = *(const float4*)(wq + i);
    uint2 p; p.x = pack2(v.x, v.y); p.y = pack2(v.z, v.w);
    *(uint2*)(wqb + i) = p;
    return;
  }
  int row = blockIdx.x - QKVCVT;
  size_t base = (size_t)row * Cc;
  float v[3];
  #pragma unroll
  for (int i = 0; i < 3; ++i) v[i] = xin[base + tid + i*256];
  __shared__ float red[8];
  float s = v[0]+v[1]+v[2];
  #pragma unroll
  for (int off=32; off; off>>=1) s += __shfl_xor(s, off);
  int wid = tid >> 6, lane = tid & 63;
  if (lane==0) red[wid] = s;
  __syncthreads();
  float mean = (red[0]+red[1]+red[2]+red[3]) * (1.f/Cc);
  float dd = 0.f;
  #pragma unroll
  for (int i=0;i<3;++i){ float t = v[i]-mean; dd += t*t; }
  #pragma unroll
  for (int off=32; off; off>>=1) dd += __shfl_xor(dd, off);
  if (lane==0) red[4+wid] = dd;
  __syncthreads();
  float var  = (red[4]+red[5]+red[6]+red[7]) * (1.f/Cc);
  float rstd = rsqrtf(var + 1e-5f);
  #pragma unroll
  for (int i=0;i<3;++i){
    int idx = tid + i*256;
    xout[base+idx] = f2b((v[i]-mean)*rstd*g1[idx] + be1[idx]);
  }
}

// ---------------- LayerNorm (f32 in, bf16 out) — used for LN2 ----------------
__global__ __launch_bounds__(256) void ln_kernel(const float* __restrict__ in,
    const float* __restrict__ g, const float* __restrict__ be, ushort_t* __restrict__ out)
{
  int row = blockIdx.x;
  int tid = threadIdx.x;
  size_t base = (size_t)row * Cc;
  float v[3];
  #pragma unroll
  for (int i = 0; i < 3; ++i) v[i] = in[base + tid + i*256];
  __shared__ float red[8];
  float s = v[0]+v[1]+v[2];
  #pragma unroll
  for (int off=32; off; off>>=1) s += __shfl_xor(s, off);
  int wid = tid >> 6, lane = tid & 63;
  if (lane==0) red[wid] = s;
  __syncthreads();
  float mean = (red[0]+red[1]+red[2]+red[3]) * (1.f/Cc);
  float d = 0.f;
  #pragma unroll
  for (int i=0;i<3;++i){ float t = v[i]-mean; d += t*t; }
  #pragma unroll
  for (int off=32; off; off>>=1) d += __shfl_xor(d, off);
  if (lane==0) red[4+wid] = d;
  __syncthreads();
  float var  = (red[4]+red[5]+red[6]+red[7]) * (1.f/Cc);
  float rstd = rsqrtf(var + 1e-5f);
  #pragma unroll
  for (int i=0;i<3;++i){
    int idx = tid + i*256;
    out[base+idx] = f2b((v[i]-mean)*rstd*g[idx] + be[idx]);
  }
}

// ---------------- MFMA GEMM: out[M,Nd] = A[M,K] @ W[Nd,K]^T (+epilogue) ----------------
// Tile 128 x NT (NT=128 or 64), BK=64 (two stacked [*][32] halves), double-buffered.
// EPI: 1 +bias+resid_f32 -> f32 | 2 +bias,GELU->bf16
// XCD-aware block swizzle (R15): all grids % 8 == 0, remap bijective.
template<int EPI, int NT>
__global__ __launch_bounds__(256) void mgemm_kernel(
    const ushort_t* __restrict__ A, const ushort_t* __restrict__ W,
    const float* __restrict__ bias, const float* __restrict__ residf,
    void* __restrict__ outv, int Nd, int K)
{
  constexpr int JT = NT/32;           // n-subtiles per wave
  __shared__ __align__(16) ushort_t As[2][2][128*32];   // [buf][kk][row*32]
  __shared__ __align__(16) ushort_t Ws[2][2][NT*32];
  int tid = threadIdx.x;
  int w = tid >> 6, lane = tid & 63;
  int g = lane >> 4, c = lane & 15;
  int wr = w >> 1, wc = w & 1;
  int gx = gridDim.x;
  int nwg = gx * gridDim.y;
  int lin = blockIdx.y * gx + blockIdx.x;
  int swz = (lin & 7) * (nwg >> 3) + (lin >> 3);
  int bx = swz % gx, by = swz / gx;
  int m0 = by * 128, n0 = bx * NT;
  int schunk = (lane & 3) * 8;
  const ushort_t* Ag = A + (size_t)(m0 + w*32 + (lane >> 2))*K + schunk;
  const ushort_t* Wg;
  if constexpr (NT == 128) Wg = W + (size_t)(n0 + w*32 + (lane >> 2))*K + schunk;
  else                     Wg = W + (size_t)(n0 + w*16 + (lane >> 2))*K + schunk;
  int wAoff = w*1024;
  int wWoff = (NT == 128) ? w*1024 : w*512;
  f4v acc[4][JT] = {};

  auto stage = [&](int bf, int k0s){
    GLD16(Ag + k0s,             &As[bf][0][wAoff]);
    GLD16(Ag + 16*K + k0s,      &As[bf][0][wAoff + 512]);
    GLD16(Ag + k0s + 32,        &As[bf][1][wAoff]);
    GLD16(Ag + 16*K + k0s + 32, &As[bf][1][wAoff + 512]);
    GLD16(Wg + k0s,             &Ws[bf][0][wWoff]);
    GLD16(Wg + k0s + 32,        &Ws[bf][1][wWoff]);
    if constexpr (NT == 128) {
      GLD16(Wg + 16*K + k0s,      &Ws[bf][0][wWoff + 512]);
      GLD16(Wg + 16*K + k0s + 32, &Ws[bf][1][wWoff + 512]);
    }
  };

  stage(0, 0);
  __syncthreads();

  int nk = K >> 6;
  for (int t = 0; t < nk; ++t) {
    int cur = t & 1;
    if (t + 1 < nk) stage(cur ^ 1, (t + 1) << 6);
    #pragma unroll
    for (int kk = 0; kk < 2; ++kk){
      s8v af[4], wf[JT];
      #pragma unroll
      for (int i=0;i<4;++i) af[i] = *(const s8v*)&As[cur][kk][(wr*64 + i*16 + c)*32 + g*8];
      #pragma unroll
      for (int j=0;j<JT;++j) wf[j] = *(const s8v*)&Ws[cur][kk][(wc*(NT/2) + j*16 + c)*32 + g*8];
      #pragma unroll
      for (int i=0;i<4;++i)
        #pragma unroll
        for (int j=0;j<JT;++j)
          acc[i][j] = __builtin_amdgcn_mfma_f32_16x16x32_bf16(af[i], wf[j], acc[i][j], 0,0,0);
    }
    __syncthreads();
  }
  #pragma unroll
  for (int j=0;j<JT;++j){
    int col = n0 + wc*(NT/2) + j*16 + c;
    float bv = bias[col];
    #pragma unroll
    for (int i=0;i<4;++i){
      int row0 = m0 + wr*64 + i*16 + g*4;
      #pragma unroll
      for (int r=0;r<4;++r){
        float v = acc[i][j][r];
        size_t off = (size_t)(row0 + r)*Nd + col;
        if (EPI == 2) {
          float t = v + bv;
          ((ushort_t*)outv)[off] = f2b(0.5f*t*(1.0f + erff(t*0.70710678118654752f)));
        } else {
          ((float*)outv)[off] = v + bv + residf[off];
        }
      }
    }
  }
}

// ---------------- QKV GEMM with fused RoPE repack epilogue (R18) ----------------
// BK=64 dbuf main loop (R19). Epilogue: region = n0/768 (0=q,1=k,2=v; blocks
// never straddle since 768%128==0). q/k: RoPE pairs (acc[i][0],acc[i][1]) with
// y-tables, (acc[i][2],acc[i][3]) with x-tables, table idx c / 16+c, q scaled
// by 0.125*log2e. v: uint2 of 4 consecutive tokens at fixed dim into Vt.
__global__ __launch_bounds__(256) void qkvgemm_kernel(
    const ushort_t* __restrict__ A, const ushort_t* __restrict__ W,
    const float* __restrict__ cx, const float* __restrict__ sx,
    const float* __restrict__ cy, const float* __restrict__ sy,
    ushort_t* __restrict__ Qb, ushort_t* __restrict__ Kb, ushort_t* __restrict__ Vt)
{
  constexpr int NT = 128, JT = 4, K = 768;
  __shared__ __align__(16) ushort_t As[2][2][128*32];
  __shared__ __align__(16) ushort_t Ws[2][2][NT*32];
  int tid = threadIdx.x;
  int w = tid >> 6, lane = tid & 63;
  int g = lane >> 4, c = lane & 15;
  int wr = w >> 1, wc = w & 1;
  int gx = gridDim.x;
  int nwg = gx * gridDim.y;
  int lin = blockIdx.y * gx + blockIdx.x;
  int swz = (lin & 7) * (nwg >> 3) + (lin >> 3);
  int bx = swz % gx, by = swz / gx;
  int m0 = by * 128, n0 = bx * NT;
  int schunk = (lane & 3) * 8;
  const ushort_t* Ag = A + (size_t)(m0 + w*32 + (lane >> 2))*K + schunk;
  const ushort_t* Wg = W + (size_t)(n0 + w*32 + (lane >> 2))*K + schunk;
  int wAoff = w*1024;
  f4v acc[4][JT] = {};

  auto stage = [&](int bf, int k0s){
    GLD16(Ag + k0s,             &As[bf][0][wAoff]);
    GLD16(Ag + 16*K + k0s,      &As[bf][0][wAoff + 512]);
    GLD16(Ag + k0s + 32,        &As[bf][1][wAoff]);
    GLD16(Ag + 16*K + k0s + 32, &As[bf][1][wAoff + 512]);
    GLD16(Wg + k0s,             &Ws[bf][0][wAoff]);
    GLD16(Wg + 16*K + k0s,      &Ws[bf][0][wAoff + 512]);
    GLD16(Wg + k0s + 32,        &Ws[bf][1][wAoff]);
    GLD16(Wg + 16*K + k0s + 32, &Ws[bf][1][wAoff + 512]);
  };

  stage(0, 0);
  __syncthreads();

  int nk = K >> 6;
  for (int t = 0; t < nk; ++t) {
    int cur = t & 1;
    if (t + 1 < nk) stage(cur ^ 1, (t + 1) << 6);
    #pragma unroll
    for (int kk = 0; kk < 2; ++kk){
      s8v af[4], wf[JT];
      #pragma unroll
      for (int i=0;i<4;++i) af[i] = *(const s8v*)&As[cur][kk][(wr*64 + i*16 + c)*32 + g*8];
      #pragma unroll
      for (int j=0;j<JT;++j) wf[j] = *(const s8v*)&Ws[cur][kk][(wc*64 + j*16 + c)*32 + g*8];
      #pragma unroll
      for (int i=0;i<4;++i)
        #pragma unroll
        for (int j=0;j<JT;++j)
          acc[i][j] = __builtin_amdgcn_mfma_f32_16x16x32_bf16(af[i], wf[j], acc[i][j], 0,0,0);
    }
    __syncthreads();
  }

  int region = n0 / 768;                 // 0=q, 1=k, 2=v (uniform per block)
  int h = ((n0 - region*768) >> 6) + wc; // head index
  if (region < 2) {
    float sc = region ? 1.0f : 0.18033688011112042f;   // q: 0.125 * log2(e)
    ushort_t* dstb = region ? Kb : Qb;
    #pragma unroll
    for (int i=0;i<4;++i){
      int row0 = m0 + wr*64 + i*16 + g*4;
      #pragma unroll
      for (int r=0;r<4;++r){
        int row = row0 + r;
        int b = row >= Nn;
        int nt = row - (b ? Nn : 0);
        size_t tb = (size_t)nt*32 + c;
        float vlo0 = acc[i][0][r], vhi0 = acc[i][1][r];
        float vlo1 = acc[i][2][r], vhi1 = acc[i][3][r];
        float o0 = (vlo0*cy[tb]    - vhi0*sy[tb])    * sc;
        float o1 = (vhi0*cy[tb+16] + vlo0*sy[tb+16]) * sc;
        float o2 = (vlo1*cx[tb]    - vhi1*sx[tb])    * sc;
        float o3 = (vhi1*cx[tb+16] + vlo1*sx[tb+16]) * sc;
        ushort_t* dp = dstb + ((size_t)(b*Hh + h)*Nn + nt)*64;
        dp[c]      = f2b(o0);
        dp[16 + c] = f2b(o1);
        dp[32 + c] = f2b(o2);
        dp[48 + c] = f2b(o3);
      }
    }
  } else {
    #pragma unroll
    for (int i=0;i<4;++i){
      int row0 = m0 + wr*64 + i*16 + g*4;
      int b = row0 >= Nn;
      int nt0 = row0 - (b ? Nn : 0);
      #pragma unroll
      for (int j=0;j<4;++j){
        int d = j*16 + c;
        uint2 pk;
        pk.x = pack2(acc[i][j][0], acc[i][j][1]);
        pk.y = pack2(acc[i][j][2], acc[i][j][3]);
        *(uint2*)&Vt[((size_t)(b*Hh + h)*64 + d)*Nn + nt0] = pk;
      }
    }
  }
}

// ---------------- MFMA flash attention v3b (verified ~130 us) + cvt piggyback ----------
// split-key waves, XCD-pinned heads: fattn blocks at y<48: (x=bh=24, y=qtile=48)
// -> xcd = bh%8, KV working set 2.3 MB < 4 MB L2/XCD. K/V direct global->VGPR.
// Blocks y>=48 (5184 tiny blocks) convert wproj/wfc1/wfc2 fp32->bf16 (R22).
// DO NOT: unroll/rotate (R9/R20), remove the fence (R14), VALU rowsums (R24 —
// spills even with fence kept; the l-MFMAs accumulate in AGPRs and are the
// register-cheapest rowsum), smaller key tiles (R13), wave re-balance (R10-R12).
__global__ __launch_bounds__(256, 3) void fattn_kernel(
    const ushort_t* __restrict__ Qb, const ushort_t* __restrict__ Kb,
    const ushort_t* __restrict__ Vt, ushort_t* __restrict__ ob,
    const float* __restrict__ wp,  ushort_t* __restrict__ wpb,
    const float* __restrict__ w1,  ushort_t* __restrict__ w1b,
    const float* __restrict__ w2,  ushort_t* __restrict__ w2b)
{
  int tid = threadIdx.x;
  if (blockIdx.y >= 48) {
    // weight-convert path: wproj 589824 | wfc1 2359296 | wfc2 2359296 elems
    int cvtIdx = (blockIdx.y - 48)*24 + blockIdx.x;
    int i = cvtIdx*1024 + tid*4;
    const float* src; ushort_t* dst;
    if (i < 589824)       { src = wp + i;            dst = wpb + i; }
    else if (i < 2949120) { src = w1 + (i-589824);   dst = w1b + (i-589824); }
    else                  { src = w2 + (i-2949120);  dst = w2b + (i-2949120); }
    float4 v = *(const float4*)src;
    uint2 p; p.x = pack2(v.x, v.y); p.y = pack2(v.z, v.w);
    *(uint2*)dst = p;
    return;
  }
  __shared__ __align__(16) char smem[36864];  // [w][qs][16][72] bf16 P; aliases [w][64][72] Or
  __shared__ float Lred[256];
  int bh = blockIdx.x;
  int q0 = blockIdx.y * 64;
  int w = tid >> 6, lane = tid & 63, g = lane >> 4, c = lane & 15;

  const ushort_t* kbase = Kb + (size_t)bh*Nn*64;
  const ushort_t* vbase = Vt + (size_t)bh*64*Nn;

  s8v qf0[4], qf1[4];
  #pragma unroll
  for (int qs=0;qs<4;++qs){
    const ushort_t* qp = Qb + ((size_t)bh*Nn + q0 + qs*16 + c)*64;
    qf0[qs] = *(const s8v*)(qp + g*8);
    qf1[qs] = *(const s8v*)(qp + 32 + g*8);
  }
  s8v ones8;
  #pragma unroll
  for (int j=0;j<8;++j) ones8[j] = (short)0x3f80;   // bf16 1.0

  f4v o[4][4] = {};
  f4v l[4] = {};
  ushort_t* pw = (ushort_t*)smem + w*4608;   // wave-private 4*16*72

  for (int it = 0; it < 12; ++it){
    int key0 = (it*4 + w) * 64;
    // K fragments direct from global (A-operand: A[m=key][k=dim])
    s8v ka[4], kb2[4];
    #pragma unroll
    for (int ks=0;ks<4;++ks){
      const ushort_t* kr = kbase + (size_t)(key0 + ks*16 + c)*64 + g*8;
      ka[ks]  = *(const s8v*)(kr);
      kb2[ks] = *(const s8v*)(kr + 32);
    }
    // S^T = K·Q^T per q-subtile; p = exp2(s) -> wave-private LDS
    #pragma unroll
    for (int qs=0;qs<4;++qs){
      #pragma unroll
      for (int ks=0;ks<4;++ks){
        f4v z = {0,0,0,0};
        z = __builtin_amdgcn_mfma_f32_16x16x32_bf16(ka[ks],  qf0[qs], z, 0,0,0);
        z = __builtin_amdgcn_mfma_f32_16x16x32_bf16(kb2[ks], qf1[qs], z, 0,0,0);
        uint2 pk;
        pk.x = pack2t(__builtin_amdgcn_exp2f(z[0]), __builtin_amdgcn_exp2f(z[1]));
        pk.y = pack2t(__builtin_amdgcn_exp2f(z[2]), __builtin_amdgcn_exp2f(z[3]));
        *(uint2*)&pw[qs*1152 + c*72 + ks*16 + g*4] = pk;
      }
    }
    asm volatile("s_waitcnt lgkmcnt(0)" ::: "memory");
    // V^T fragments direct from global (A-operand: A[m=dim][k=key])
    s8v va[4], vb[4];
    #pragma unroll
    for (int d=0;d<4;++d){
      const ushort_t* vr = vbase + (size_t)(d*16 + c)*Nn + key0 + g*8;
      va[d] = *(const s8v*)(vr);
      vb[d] = *(const s8v*)(vr + 32);
    }
    #pragma unroll
    for (int qs=0;qs<4;++qs){
      s8v pf0 = *(const s8v*)&pw[qs*1152 + c*72 + g*8];
      s8v pf1 = *(const s8v*)&pw[qs*1152 + c*72 + 32 + g*8];
      #pragma unroll
      for (int d=0;d<4;++d){
        o[qs][d] = __builtin_amdgcn_mfma_f32_16x16x32_bf16(va[d], pf0, o[qs][d], 0,0,0);
        o[qs][d] = __builtin_amdgcn_mfma_f32_16x16x32_bf16(vb[d], pf1, o[qs][d], 0,0,0);
      }
      l[qs] = __builtin_amdgcn_mfma_f32_16x16x32_bf16(ones8, pf0, l[qs], 0,0,0);
      l[qs] = __builtin_amdgcn_mfma_f32_16x16x32_bf16(ones8, pf1, l[qs], 0,0,0);
    }
  }

  // partials -> LDS (own slice; in-order DS makes this safe after the last P read)
  ushort_t* Or = (ushort_t*)smem;   // [w*64 + qrow][72]
  #pragma unroll
  for (int qs=0;qs<4;++qs){
    #pragma unroll
    for (int d=0;d<4;++d){
      uint2 pk;
      pk.x = pack2(o[qs][d][0], o[qs][d][1]);
      pk.y = pack2(o[qs][d][2], o[qs][d][3]);
      *(uint2*)&Or[(w*64 + qs*16 + c)*72 + d*16 + g*4] = pk;
    }
    Lred[w*64 + qs*16 + c] = l[qs][0];
  }
  __syncthreads();

  // combine: thread t owns (qrow = t>>2, dims (t&3)*16..+16)
  int qrow = tid >> 2, dseg = (tid & 3) * 16;
  float acc[16] = {};
  #pragma unroll
  for (int w2=0;w2<4;++w2){
    const ushort_t* base = &Or[(w2*64 + qrow)*72 + dseg];
    uint4 u0 = *(const uint4*)(base);
    uint4 u1 = *(const uint4*)(base + 8);
    u32 uu[8] = {u0.x,u0.y,u0.z,u0.w,u1.x,u1.y,u1.z,u1.w};
    #pragma unroll
    for (int j=0;j<8;++j){
      acc[j*2]   += b2f((ushort_t)(uu[j] & 0xffff));
      acc[j*2+1] += b2f((ushort_t)(uu[j] >> 16));
    }
  }
  float rl = 1.0f / (Lred[qrow] + Lred[64+qrow] + Lred[128+qrow] + Lred[192+qrow]);
  int b = bh / Hh, h = bh - b*Hh;
  ushort_t* op = ob + ((size_t)b*Nn + q0 + qrow)*768 + h*64 + dseg;
  uint4 w0_, w1_;
  w0_.x = pack2(acc[0]*rl, acc[1]*rl);   w0_.y = pack2(acc[2]*rl, acc[3]*rl);
  w0_.z = pack2(acc[4]*rl, acc[5]*rl);   w0_.w = pack2(acc[6]*rl, acc[7]*rl);
  w1_.x = pack2(acc[8]*rl, acc[9]*rl);   w1_.y = pack2(acc[10]*rl, acc[11]*rl);
  w1_.z = pack2(acc[12]*rl, acc[13]*rl); w1_.w = pack2(acc[14]*rl, acc[15]*rl);
  *(uint4*)(op)     = w0_;
  *(uint4*)(op + 8) = w1_;
}

extern "C" void kernel_launch(void* const* d_in, const int* in_sizes, int n_in,
                              void* d_out, int out_size, void* d_ws, size_t ws_size,
                              hipStream_t stream)
{
  const float* x      = (const float*)d_in[0];
  const float* w_qkv  = (const float*)d_in[1];
  const float* w_proj = (const float*)d_in[2];
  const float* b_proj = (const float*)d_in[3];
  const float* g1     = (const float*)d_in[4];
  const float* be1    = (const float*)d_in[5];
  const float* g2     = (const float*)d_in[6];
  const float* be2    = (const float*)d_in[7];
  const float* w_fc1  = (const float*)d_in[8];
  const float* b_fc1  = (const float*)d_in[9];
  const float* w_fc2  = (const float*)d_in[10];
  const float* b_fc2  = (const float*)d_in[11];
  const float* cx     = (const float*)d_in[12];
  const float* sx     = (const float*)d_in[13];
  const float* cy     = (const float*)d_in[14];
  const float* sy     = (const float*)d_in[15];
  float* out = (float*)d_out;

  char* ws = (char*)d_ws;
  ushort_t* xnb   = (ushort_t*)(ws);
  ushort_t* Qb    = (ushort_t*)(ws + 9437184);
  ushort_t* Kb    = (ushort_t*)(ws + 18874368);
  float*    x1    = (float*)   (ws + 9437184);    // overlays dead Qb+Kb (live 5-8)
  ushort_t* Vt    = (ushort_t*)(ws + 28311552);
  ushort_t* obb   = (ushort_t*)(ws + 37748736);
  ushort_t* hb    = (ushort_t*)(ws + 47185920);
  ushort_t* wqkvb = (ushort_t*)(ws + 84934656);
  ushort_t* wprojb= (ushort_t*)(ws + 88473600);
  ushort_t* wfc1b = (ushort_t*)(ws + 89653248);
  ushort_t* wfc2b = (ushort_t*)(ws + 94371840);

  // 0+1) wqkv -> bf16 AND LN1 -> bf16, one fused launch (other weights piggyback on fattn)
  cvtln_kernel<<<QKVCVT + Mm, 256, 0, stream>>>(w_qkv, wqkvb, x, g1, be1, xnb);

  // 2+3) QKV GEMM with fused RoPE repack -> Qb, Kb, Vt
  qkvgemm_kernel<<<dim3(2304/128, Mm/128), 256, 0, stream>>>(
      xnb, wqkvb, cx, sx, cy, sy, Qb, Kb, Vt);
  // 4) fattn v3b (y<48) + wproj/wfc1/wfc2 conversion piggyback (y>=48, 5184 blocks)
  fattn_kernel<<<dim3(24, 48 + 216), 256, 0, stream>>>(
      Qb, Kb, Vt, obb, w_proj, wprojb, w_fc1, wfc1b, w_fc2, wfc2b);
  // 5) x1 = x + obb @ w_proj^T + b_proj (f32) — 128x64 tiles, 576 blocks (tail-free @3/CU)
  mgemm_kernel<1,64><<<dim3(768/64, Mm/128), 256, 0, stream>>>(obb, wprojb, b_proj, x, x1, 768, 768);
  // 6) LN2 -> bf16
  ln_kernel<<<Mm, 256, 0, stream>>>(x1, g2, be2, xnb);
  // 7) h = gelu(xn @ w_fc1^T + b_fc1) -> bf16 — NT=64: 2304 blocks = exactly 3 rounds @768 cap
  mgemm_kernel<2,64><<<dim3(3072/64, Mm/128), 256, 0, stream>>>(xnb, wfc1b, b_fc1, nullptr, hb, 3072, 768);
  // 8) out = x1 + h @ w_fc2^T + b_fc2 (f32) — 128x64 tiles, 576 blocks (tail-free @3/CU)
  mgemm_kernel<1,64><<<dim3(768/64, Mm/128), 256, 0, stream>>>(hb, wfc2b, b_fc2, x1, out, 768, 3072);
}